// Round 2
// baseline (409.700 us; speedup 1.0000x reference)
//
#include <hip/hip_runtime.h>
#include <hip/hip_bf16.h>
#include <type_traits>

// ---------------------------------------------------------------------------
// ViLLayer forward, round 1: fix output dtype (reference output is FP32).
//   k1: up-proj GEMM fp32 (x @ W_up^T + b)            -> x_inner [4096][1536]
//   k2: depthwise 3x3 conv + bias + SiLU              -> conv_act [4096][768]
//   k3: headwise 4x4 q,k,v (+bf16 copies) + gate dots -> qbf/kbf/vbf, ig/fg
//   k4: per-(b,h) scan: lfc=cumsum(logsig(fg)), a=ig-lfc, runmax=cummax(a)
//   k5: mLSTM attention (bf16 MFMA 16x16x32) + fused groupnorm/skip/z-gate
//   k6: down-proj GEMM fp32 -> fp32 output
// ---------------------------------------------------------------------------

#define B_     4
#define S_     1024
#define DIM_   384
#define INNER_ 768
#define NHM_   4
#define DH_    192
#define NTOK   (B_*S_)      // 4096

typedef __attribute__((ext_vector_type(8))) __bf16 bf16x8v;
typedef __attribute__((ext_vector_type(4))) float  f32x4;

static __device__ __forceinline__ f32x4 mfma16(bf16x8v a, bf16x8v b, f32x4 c) {
  return __builtin_amdgcn_mfma_f32_16x16x32_bf16(a, b, c, 0, 0, 0);
}

// ---------------- GEMM: C[M][N] = A[M][K] * Bw[N][K]^T + bias --------------
template<typename OutT>
__global__ __launch_bounds__(256) void gemm_rt(
    const float* __restrict__ A, const float* __restrict__ Bw,
    const float* __restrict__ bias, OutT* __restrict__ C,
    int M, int N, int Kd)
{
  __shared__ float As[16][64];
  __shared__ float Bs[16][64];
  const int tid = threadIdx.x;
  const int m0 = blockIdx.y * 64, n0 = blockIdx.x * 64;
  const int tx = tid & 15, ty = tid >> 4;
  float acc[4][4] = {};
  for (int k0 = 0; k0 < Kd; k0 += 16) {
    __syncthreads();
    #pragma unroll
    for (int i = 0; i < 4; ++i) {
      const int idx = tid + i * 256;
      const int mm = idx >> 4, kk = idx & 15;
      As[kk][mm] = A[(size_t)(m0 + mm) * Kd + (k0 + kk)];
      Bs[kk][mm] = Bw[(size_t)(n0 + mm) * Kd + (k0 + kk)];
    }
    __syncthreads();
    #pragma unroll
    for (int kk = 0; kk < 16; ++kk) {
      const float4 a = *(const float4*)(&As[kk][ty * 4]);
      const float4 b = *(const float4*)(&Bs[kk][tx * 4]);
      acc[0][0] += a.x*b.x; acc[0][1] += a.x*b.y; acc[0][2] += a.x*b.z; acc[0][3] += a.x*b.w;
      acc[1][0] += a.y*b.x; acc[1][1] += a.y*b.y; acc[1][2] += a.y*b.z; acc[1][3] += a.y*b.w;
      acc[2][0] += a.z*b.x; acc[2][1] += a.z*b.y; acc[2][2] += a.z*b.z; acc[2][3] += a.z*b.w;
      acc[3][0] += a.w*b.x; acc[3][1] += a.w*b.y; acc[3][2] += a.w*b.z; acc[3][3] += a.w*b.w;
    }
  }
  #pragma unroll
  for (int i = 0; i < 4; ++i) {
    const int m = m0 + ty * 4 + i;
    #pragma unroll
    for (int j = 0; j < 4; ++j) {
      const int n = n0 + tx * 4 + j;
      const float v = acc[i][j] + bias[n];
      if constexpr (std::is_same<OutT, float>::value) {
        C[(size_t)m * N + n] = v;
      } else {
        C[(size_t)m * N + n] = __float2bfloat16(v);
      }
    }
  }
}

// ---------------- depthwise 3x3 conv + bias + SiLU -------------------------
__global__ __launch_bounds__(256) void conv_silu_k(
    const float* __restrict__ xi, const float* __restrict__ cw,
    const float* __restrict__ cb, float* __restrict__ ca)
{
  const int idx = blockIdx.x * 256 + threadIdx.x;
  if (idx >= NTOK * INNER_) return;
  const int c = idx % INNER_;
  const int t = idx / INNER_;
  const int s = t & 1023;
  const int y = s >> 5, x = s & 31;
  const int tb = t - s;                       // b*1024
  float acc = cb[c];
  #pragma unroll
  for (int ky = -1; ky <= 1; ++ky) {
    const int yy = y + ky;
    if (yy < 0 || yy > 31) continue;
    #pragma unroll
    for (int kx = -1; kx <= 1; ++kx) {
      const int xx = x + kx;
      if (xx < 0 || xx > 31) continue;
      acc += xi[(size_t)(tb + (yy << 5) + xx) * 1536 + c]
           * cw[((ky + 1) * 3 + (kx + 1)) * INNER_ + c];
    }
  }
  ca[(size_t)t * INNER_ + c] = acc / (1.f + __expf(-acc));
}

// ---------------- headwise q,k,v + gate pre-activations --------------------
__global__ __launch_bounds__(256) void headwise_gates_k(
    const float* __restrict__ xi, const float* __restrict__ ca,
    const float* __restrict__ Wq, const float* __restrict__ bq,
    const float* __restrict__ Wk, const float* __restrict__ bk,
    const float* __restrict__ Wv, const float* __restrict__ bv,
    const float* __restrict__ Wig, const float* __restrict__ big,
    const float* __restrict__ Wfg, const float* __restrict__ bfg,
    __hip_bfloat16* __restrict__ qbf, __hip_bfloat16* __restrict__ kbf,
    __hip_bfloat16* __restrict__ vbf,
    float* __restrict__ ig, float* __restrict__ fg)
{
  __shared__ float qs[INNER_], ks[INNER_], vs[INNER_];
  const int t = blockIdx.x;
  const int b = t >> 10, s = t & 1023;
  const int tid = threadIdx.x;
  if (tid < 192) {
    float cav[4], xmv[4];
    #pragma unroll
    for (int d = 0; d < 4; ++d) {
      cav[d] = ca[(size_t)t * INNER_ + tid * 4 + d];
      xmv[d] = xi[(size_t)t * 1536 + tid * 4 + d];
    }
    #pragma unroll
    for (int o = 0; o < 4; ++o) {
      const int cidx = tid * 4 + o;
      float q = bq[cidx], k = bk[cidx], v = bv[cidx];
      #pragma unroll
      for (int d = 0; d < 4; ++d) {
        q += cav[d] * Wq[tid * 16 + o * 4 + d];
        k += cav[d] * Wk[tid * 16 + o * 4 + d];
        v += xmv[d] * Wv[tid * 16 + o * 4 + d];
      }
      qs[cidx] = q; ks[cidx] = k; vs[cidx] = v;
      const int hm = cidx / DH_, dd = cidx % DH_;
      const size_t o2 = ((size_t)(b * NHM_ + hm) * S_ + s) * DH_ + dd;
      qbf[o2] = __float2bfloat16(q);
      kbf[o2] = __float2bfloat16(k);
      vbf[o2] = __float2bfloat16(v);
    }
  }
  __syncthreads();
  // 8 groups of 32 threads: g<4 -> ig head g, g>=4 -> fg head g-4
  const int g = tid >> 5, l32 = tid & 31;
  const float* Wg = (g < 4) ? Wig : Wfg;
  const int h = g & 3;
  float sum = 0.f;
  for (int c = l32; c < INNER_; c += 32) {
    sum += qs[c] * Wg[h * 2304 + c]
         + ks[c] * Wg[h * 2304 + 768 + c]
         + vs[c] * Wg[h * 2304 + 1536 + c];
  }
  #pragma unroll
  for (int m = 16; m >= 1; m >>= 1) sum += __shfl_xor(sum, m);
  if (l32 == 0) {
    if (g < 4) ig[(size_t)(b * NHM_ + h) * S_ + s] = sum + big[h];
    else       fg[(size_t)(b * NHM_ + h) * S_ + s] = sum + bfg[h];
  }
}

// ---------------- per-(b,h) scans: lfc, a = ig-lfc, runmax = cummax(a) -----
__global__ __launch_bounds__(64) void gate_scan_k(
    const float* __restrict__ ig, const float* __restrict__ fg,
    float* __restrict__ lfc, float* __restrict__ aa, float* __restrict__ rm)
{
  const int bh = blockIdx.x;
  const int lane = threadIdx.x;          // 64 lanes, 16 elems each
  const float* fgp = fg + bh * S_;
  const float* igp = ig + bh * S_;
  float v[16];
  float run = 0.f;
  #pragma unroll
  for (int i = 0; i < 16; ++i) {
    const float x = fgp[lane * 16 + i];
    const float lf = fminf(x, 0.f) - log1pf(expf(-fabsf(x)));   // log_sigmoid
    run += lf;
    v[i] = run;
  }
  float inc = run;
  #pragma unroll
  for (int off = 1; off < 64; off <<= 1) {
    const float o = __shfl_up(inc, off);
    if (lane >= off) inc += o;
  }
  const float excl = inc - run;
  float rv[16];
  float rmx = -INFINITY;
  #pragma unroll
  for (int i = 0; i < 16; ++i) {
    const float l = v[i] + excl;
    lfc[bh * S_ + lane * 16 + i] = l;
    const float a = igp[lane * 16 + i] - l;
    aa[bh * S_ + lane * 16 + i] = a;
    rmx = fmaxf(rmx, a);
    rv[i] = rmx;
  }
  float incm = rmx;
  #pragma unroll
  for (int off = 1; off < 64; off <<= 1) {
    const float o = __shfl_up(incm, off);
    if (lane >= off) incm = fmaxf(incm, o);
  }
  float exm = __shfl_up(incm, 1);
  if (lane == 0) exm = -INFINITY;
  #pragma unroll
  for (int i = 0; i < 16; ++i) {
    rm[bh * S_ + lane * 16 + i] = fmaxf(rv[i], exm);
  }
}

// ---------------- mLSTM attention + fused epilogue -------------------------
// grid: (S/64, B*NHM), block 256 (4 waves). Wave w owns q-rows [q0b+16w, +16).
// MFMA 16x16x32 bf16. A-frag: lane holds A[l&15][(l>>4)*8+e];
// B-frag: lane holds B[(l>>4)*8+e][l&15]; D: lane holds D[(l>>4)*4+r][l&15].
__global__ __launch_bounds__(256) void mlstm_attn_k(
    const __hip_bfloat16* __restrict__ qbf, const __hip_bfloat16* __restrict__ kbf,
    const __hip_bfloat16* __restrict__ vbf,
    const float* __restrict__ lfc, const float* __restrict__ aa,
    const float* __restrict__ rm,
    const float* __restrict__ ca, const float* __restrict__ xi,
    const float* __restrict__ nw, const float* __restrict__ nb,
    const float* __restrict__ skip, float* __restrict__ hs)
{
  __shared__ __hip_bfloat16 VT[192][40];     // V^T tile, padded rows (80B)
  __shared__ __hip_bfloat16 Pl[4][16][40];   // per-wave P tile, padded rows
  const int bh = blockIdx.y;
  const int b = bh >> 2, hm = bh & 3;
  const int q0b = blockIdx.x * 64;
  const int wave = threadIdx.x >> 6, lane = threadIdx.x & 63;
  const int lrow = lane & 15, lgrp = lane >> 4;
  const int q0 = q0b + wave * 16;
  const __hip_bfloat16* Q  = qbf + (size_t)bh * S_ * DH_;
  const __hip_bfloat16* Kp = kbf + (size_t)bh * S_ * DH_;
  const __hip_bfloat16* Vp = vbf + (size_t)bh * S_ * DH_;
  const float* aap  = aa  + bh * S_;
  const float* rmp  = rm  + bh * S_;
  const float* lfcp = lfc + bh * S_;

  // Q fragments (row-major load, 16B each), reused across all j-tiles
  bf16x8v qf[6];
  #pragma unroll
  for (int kk = 0; kk < 6; ++kk)
    qf[kk] = *(const bf16x8v*)&Q[(size_t)(q0 + lrow) * DH_ + kk * 32 + lgrp * 8];

  float rmi[4];
  #pragma unroll
  for (int r = 0; r < 4; ++r) rmi[r] = rmp[q0 + lgrp * 4 + r];

  const f32x4 zero4 = {0.f, 0.f, 0.f, 0.f};
  f32x4 hacc[12];
  #pragma unroll
  for (int dd = 0; dd < 12; ++dd) hacc[dd] = zero4;
  float rs[4] = {0.f, 0.f, 0.f, 0.f};

  const int myqmax = q0 + 15;
  const int njt = (q0b >> 5) + 2;            // j-tiles of 32 needed by block
  const float scale = 0.07216878364870323f;  // 1/sqrt(192)

  for (int jt = 0; jt < njt; ++jt) {
    const int j0 = jt * 32;
    // cooperative stage: VT[d][j] = V[j0+j][d]
    for (int i = threadIdx.x; i < 32 * 192; i += 256) {
      const int j = i / 192, d = i - j * 192;
      VT[d][j] = Vp[(size_t)(j0 + j) * DH_ + d];
    }
    __syncthreads();
    if (j0 <= myqmax) {
      f32x4 sacc[2];
      sacc[0] = zero4; sacc[1] = zero4;
      #pragma unroll
      for (int jj = 0; jj < 2; ++jj) {
        #pragma unroll
        for (int kk = 0; kk < 6; ++kk) {
          const bf16x8v kf = *(const bf16x8v*)
              &Kp[(size_t)(j0 + jj * 16 + lrow) * DH_ + kk * 32 + lgrp * 8];
          sacc[jj] = mfma16(qf[kk], kf, sacc[jj]);
        }
      }
      // weights + rowsum + P tile
      #pragma unroll
      for (int jj = 0; jj < 2; ++jj) {
        const int j = j0 + jj * 16 + lrow;
        const float aj = aap[j];
        #pragma unroll
        for (int r = 0; r < 4; ++r) {
          const int i_ = q0 + lgrp * 4 + r;
          float cval = 0.f;
          if (j <= i_) cval = sacc[jj][r] * scale * __expf(aj - rmi[r]);
          rs[r] += cval;
          Pl[wave][lgrp * 4 + r][jj * 16 + lrow] = __float2bfloat16(cval);
        }
      }
      // PV: A = P (round-trip through LDS for A-layout), B = V^T tile
      const bf16x8v pf = *(const bf16x8v*)&Pl[wave][lrow][lgrp * 8];
      #pragma unroll
      for (int dd = 0; dd < 12; ++dd) {
        const bf16x8v vf = *(const bf16x8v*)&VT[dd * 16 + lrow][lgrp * 8];
        hacc[dd] = mfma16(pf, vf, hacc[dd]);
      }
    }
    __syncthreads();
  }

  // rowsum reduce across the 16 lanes sharing lgrp
  #pragma unroll
  for (int r = 0; r < 4; ++r) {
    #pragma unroll
    for (int m = 1; m < 16; m <<= 1) rs[r] += __shfl_xor(rs[r], m);
  }
  // normalizer + groupnorm + skip + z-gate, write h_state
  #pragma unroll
  for (int r = 0; r < 4; ++r) {
    const int i_ = q0 + lgrp * 4 + r;
    const int t = b * S_ + i_;
    const float mld = lfcp[i_] + rmi[r];
    const float nrm = fmaxf(fabsf(rs[r]), __expf(-mld)) + 1e-6f;
    float hv[12];
    float sum = 0.f, sq = 0.f;
    #pragma unroll
    for (int dd = 0; dd < 12; ++dd) {
      const float x = hacc[dd][r] / nrm;
      hv[dd] = x; sum += x; sq += x * x;
    }
    #pragma unroll
    for (int m = 1; m < 16; m <<= 1) {
      sum += __shfl_xor(sum, m);
      sq  += __shfl_xor(sq, m);
    }
    const float mean = sum * (1.f / 192.f);
    const float var  = sq * (1.f / 192.f) - mean * mean;
    const float rstd = rsqrtf(var + 1e-5f);
    #pragma unroll
    for (int dd = 0; dd < 12; ++dd) {
      const int c = hm * DH_ + dd * 16 + lrow;
      const float hn = (hv[dd] - mean) * rstd * nw[c] + nb[c];
      const float cav = ca[(size_t)t * INNER_ + c];
      const float zz  = xi[(size_t)t * 1536 + 768 + c];
      const float hsv = (hn + skip[c] * cav) * (zz / (1.f + __expf(-zz)));
      hs[(size_t)t * INNER_ + c] = hsv;
    }
  }
}

// ---------------------------------------------------------------------------
extern "C" void kernel_launch(void* const* d_in, const int* in_sizes, int n_in,
                              void* d_out, int out_size, void* d_ws, size_t ws_size,
                              hipStream_t stream) {
  const float* x      = (const float*)d_in[0];
  const float* W_up   = (const float*)d_in[1];
  const float* b_up   = (const float*)d_in[2];
  const float* Wq     = (const float*)d_in[3];
  const float* bq     = (const float*)d_in[4];
  const float* Wk     = (const float*)d_in[5];
  const float* bk     = (const float*)d_in[6];
  const float* Wv     = (const float*)d_in[7];
  const float* bv     = (const float*)d_in[8];
  const float* conv_w = (const float*)d_in[9];
  const float* conv_b = (const float*)d_in[10];
  const float* W_ig   = (const float*)d_in[11];
  const float* b_ig   = (const float*)d_in[12];
  const float* W_fg   = (const float*)d_in[13];
  const float* b_fg   = (const float*)d_in[14];
  const float* norm_w = (const float*)d_in[15];
  const float* norm_b = (const float*)d_in[16];
  const float* skip   = (const float*)d_in[17];
  const float* W_down = (const float*)d_in[18];
  const float* b_down = (const float*)d_in[19];
  float* out = (float*)d_out;   // reference output dtype is float32

  char* ws = (char*)d_ws;
  constexpr size_t OFF_XI  = 0;                                    // 4096*1536 f32
  constexpr size_t OFF_CA  = OFF_XI + (size_t)NTOK * 1536 * 4;     // 4096*768 f32
  constexpr size_t OFF_QBF = OFF_CA + (size_t)NTOK * INNER_ * 4;   // 16*1024*192 bf16
  constexpr size_t OFF_KBF = OFF_QBF + (size_t)16 * S_ * DH_ * 2;
  constexpr size_t OFF_VBF = OFF_KBF + (size_t)16 * S_ * DH_ * 2;
  constexpr size_t OFF_IG  = OFF_VBF + (size_t)16 * S_ * DH_ * 2;  // 16*1024 f32
  constexpr size_t OFF_FG  = OFF_IG + (size_t)16 * S_ * 4;
  constexpr size_t OFF_LFC = OFF_FG + (size_t)16 * S_ * 4;
  constexpr size_t OFF_AA  = OFF_LFC + (size_t)16 * S_ * 4;
  constexpr size_t OFF_RM  = OFF_AA + (size_t)16 * S_ * 4;
  constexpr size_t OFF_HS  = OFF_RM + (size_t)16 * S_ * 4;         // 4096*768 f32

  float* x_inner = (float*)(ws + OFF_XI);
  float* conv_a  = (float*)(ws + OFF_CA);
  __hip_bfloat16* qbf = (__hip_bfloat16*)(ws + OFF_QBF);
  __hip_bfloat16* kbf = (__hip_bfloat16*)(ws + OFF_KBF);
  __hip_bfloat16* vbf = (__hip_bfloat16*)(ws + OFF_VBF);
  float* ig  = (float*)(ws + OFF_IG);
  float* fg  = (float*)(ws + OFF_FG);
  float* lfc = (float*)(ws + OFF_LFC);
  float* aav = (float*)(ws + OFF_AA);
  float* rmv = (float*)(ws + OFF_RM);
  float* hs  = (float*)(ws + OFF_HS);

  // 1) up-projection: x_inner = x @ W_up^T + b_up   (M=4096,N=1536,K=384)
  gemm_rt<float><<<dim3(1536 / 64, NTOK / 64), 256, 0, stream>>>(
      x, W_up, b_up, x_inner, NTOK, 1536, DIM_);
  // 2) depthwise conv + SiLU
  conv_silu_k<<<(NTOK * INNER_) / 256, 256, 0, stream>>>(
      x_inner, conv_w, conv_b, conv_a);
  // 3) headwise q,k,v + gates
  headwise_gates_k<<<NTOK, 256, 0, stream>>>(
      x_inner, conv_a, Wq, bq, Wk, bk, Wv, bv, W_ig, b_ig, W_fg, b_fg,
      qbf, kbf, vbf, ig, fg);
  // 4) gate scans
  gate_scan_k<<<16, 64, 0, stream>>>(ig, fg, lfc, aav, rmv);
  // 5) mLSTM attention + epilogue
  mlstm_attn_k<<<dim3(S_ / 64, 16), 256, 0, stream>>>(
      qbf, kbf, vbf, lfc, aav, rmv, conv_a, x_inner,
      norm_w, norm_b, skip, hs);
  // 6) down-projection -> fp32 out  (M=4096,N=384,K=768)
  gemm_rt<float><<<dim3(DIM_ / 64, NTOK / 64), 256, 0, stream>>>(
      hs, W_down, b_down, out, NTOK, DIM_, INNER_);
}

// Round 3
// 277.386 us; speedup vs baseline: 1.4770x; 1.4770x over previous
//
#include <hip/hip_runtime.h>
#include <hip/hip_bf16.h>
#include <type_traits>

// ---------------------------------------------------------------------------
// ViLLayer forward, round 2:
//   - attention split-j into balanced chunks (additive partials, since the
//     row-max is precomputed exactly) + barrier-light waves, V gathered from
//     global (L2) instead of scalar LDS transpose staging.
//   - up-proj GEMM -> bf16 MFMA (fp32 accumulate), pre-cast x & W_up.
// ---------------------------------------------------------------------------

#define B_     4
#define S_     1024
#define DIM_   384
#define INNER_ 768
#define NHM_   4
#define DH_    192
#define NTOK   (B_*S_)      // 4096
#define SLOTS_ 40           // sum over t of ceil((t+1)/4)

typedef __attribute__((ext_vector_type(8))) __bf16 bf16x8v;
typedef __attribute__((ext_vector_type(4))) float  f32x4;

static __device__ __forceinline__ f32x4 mfma16(bf16x8v a, bf16x8v b, f32x4 c) {
  return __builtin_amdgcn_mfma_f32_16x16x32_bf16(a, b, c, 0, 0, 0);
}

// ---------------- cast fp32 -> bf16 (vectorized) ---------------------------
__global__ __launch_bounds__(256) void cast_bf16_k(
    const float* __restrict__ in, __hip_bfloat16* __restrict__ out, int n4)
{
  const int i = blockIdx.x * 256 + threadIdx.x;
  if (i >= n4) return;
  const float4 v = *(const float4*)&in[i * 4];
  out[i * 4 + 0] = __float2bfloat16(v.x);
  out[i * 4 + 1] = __float2bfloat16(v.y);
  out[i * 4 + 2] = __float2bfloat16(v.z);
  out[i * 4 + 3] = __float2bfloat16(v.w);
}

// ---------------- up-proj: bf16 MFMA GEMM ----------------------------------
// C[4096][1536] = xb[4096][384] @ Wb[1536][384]^T + b.  BM=64, BN=128.
// grid (1536/128, 4096/64) = (12,64), 256 thr = 4 waves; wave w: rows w*16.
__global__ __launch_bounds__(256) void gemm_up_k(
    const __hip_bfloat16* __restrict__ xb, const __hip_bfloat16* __restrict__ Wb,
    const float* __restrict__ bias, float* __restrict__ C)
{
  const int n0 = blockIdx.x * 128, m0 = blockIdx.y * 64;
  const int wave = threadIdx.x >> 6, lane = threadIdx.x & 63;
  const int lrow = lane & 15, lgrp = lane >> 4;
  const __hip_bfloat16* xr = xb + (size_t)(m0 + wave * 16 + lrow) * DIM_;
  f32x4 acc[8];
  #pragma unroll
  for (int nt = 0; nt < 8; ++nt) acc[nt] = f32x4{0.f, 0.f, 0.f, 0.f};
  for (int k0 = 0; k0 < DIM_; k0 += 32) {
    const bf16x8v af = *(const bf16x8v*)&xr[k0 + lgrp * 8];
    #pragma unroll
    for (int nt = 0; nt < 8; ++nt) {
      const bf16x8v bf = *(const bf16x8v*)
          &Wb[(size_t)(n0 + nt * 16 + lrow) * DIM_ + k0 + lgrp * 8];
      acc[nt] = mfma16(af, bf, acc[nt]);
    }
  }
  #pragma unroll
  for (int nt = 0; nt < 8; ++nt) {
    const int n = n0 + nt * 16 + lrow;
    const float bv = bias[n];
    #pragma unroll
    for (int r = 0; r < 4; ++r) {
      const int m = m0 + wave * 16 + lgrp * 4 + r;
      C[(size_t)m * 1536 + n] = acc[nt][r] + bv;
    }
  }
}

// ---------------- GEMM fp32 (kept for down-proj) ---------------------------
template<typename OutT>
__global__ __launch_bounds__(256) void gemm_rt(
    const float* __restrict__ A, const float* __restrict__ Bw,
    const float* __restrict__ bias, OutT* __restrict__ C,
    int M, int N, int Kd)
{
  __shared__ float As[16][64];
  __shared__ float Bs[16][64];
  const int tid = threadIdx.x;
  const int m0 = blockIdx.y * 64, n0 = blockIdx.x * 64;
  const int tx = tid & 15, ty = tid >> 4;
  float acc[4][4] = {};
  for (int k0 = 0; k0 < Kd; k0 += 16) {
    __syncthreads();
    #pragma unroll
    for (int i = 0; i < 4; ++i) {
      const int idx = tid + i * 256;
      const int mm = idx >> 4, kk = idx & 15;
      As[kk][mm] = A[(size_t)(m0 + mm) * Kd + (k0 + kk)];
      Bs[kk][mm] = Bw[(size_t)(n0 + mm) * Kd + (k0 + kk)];
    }
    __syncthreads();
    #pragma unroll
    for (int kk = 0; kk < 16; ++kk) {
      const float4 a = *(const float4*)(&As[kk][ty * 4]);
      const float4 b = *(const float4*)(&Bs[kk][tx * 4]);
      acc[0][0] += a.x*b.x; acc[0][1] += a.x*b.y; acc[0][2] += a.x*b.z; acc[0][3] += a.x*b.w;
      acc[1][0] += a.y*b.x; acc[1][1] += a.y*b.y; acc[1][2] += a.y*b.z; acc[1][3] += a.y*b.w;
      acc[2][0] += a.z*b.x; acc[2][1] += a.z*b.y; acc[2][2] += a.z*b.z; acc[2][3] += a.z*b.w;
      acc[3][0] += a.w*b.x; acc[3][1] += a.w*b.y; acc[3][2] += a.w*b.z; acc[3][3] += a.w*b.w;
    }
  }
  #pragma unroll
  for (int i = 0; i < 4; ++i) {
    const int m = m0 + ty * 4 + i;
    #pragma unroll
    for (int j = 0; j < 4; ++j) {
      const int n = n0 + tx * 4 + j;
      const float v = acc[i][j] + bias[n];
      if constexpr (std::is_same<OutT, float>::value) {
        C[(size_t)m * N + n] = v;
      } else {
        C[(size_t)m * N + n] = __float2bfloat16(v);
      }
    }
  }
}

// ---------------- depthwise 3x3 conv + bias + SiLU -------------------------
__global__ __launch_bounds__(256) void conv_silu_k(
    const float* __restrict__ xi, const float* __restrict__ cw,
    const float* __restrict__ cb, float* __restrict__ ca)
{
  const int idx = blockIdx.x * 256 + threadIdx.x;
  if (idx >= NTOK * INNER_) return;
  const int c = idx % INNER_;
  const int t = idx / INNER_;
  const int s = t & 1023;
  const int y = s >> 5, x = s & 31;
  const int tb = t - s;
  float acc = cb[c];
  #pragma unroll
  for (int ky = -1; ky <= 1; ++ky) {
    const int yy = y + ky;
    if (yy < 0 || yy > 31) continue;
    #pragma unroll
    for (int kx = -1; kx <= 1; ++kx) {
      const int xx = x + kx;
      if (xx < 0 || xx > 31) continue;
      acc += xi[(size_t)(tb + (yy << 5) + xx) * 1536 + c]
           * cw[((ky + 1) * 3 + (kx + 1)) * INNER_ + c];
    }
  }
  ca[(size_t)t * INNER_ + c] = acc / (1.f + __expf(-acc));
}

// ---------------- headwise q,k,v + gate pre-activations --------------------
__global__ __launch_bounds__(256) void headwise_gates_k(
    const float* __restrict__ xi, const float* __restrict__ ca,
    const float* __restrict__ Wq, const float* __restrict__ bq,
    const float* __restrict__ Wk, const float* __restrict__ bk,
    const float* __restrict__ Wv, const float* __restrict__ bv,
    const float* __restrict__ Wig, const float* __restrict__ big,
    const float* __restrict__ Wfg, const float* __restrict__ bfg,
    __hip_bfloat16* __restrict__ qbf, __hip_bfloat16* __restrict__ kbf,
    __hip_bfloat16* __restrict__ vbf,
    float* __restrict__ ig, float* __restrict__ fg)
{
  __shared__ float qs[INNER_], ks[INNER_], vs[INNER_];
  const int t = blockIdx.x;
  const int b = t >> 10, s = t & 1023;
  const int tid = threadIdx.x;
  if (tid < 192) {
    float cav[4], xmv[4];
    #pragma unroll
    for (int d = 0; d < 4; ++d) {
      cav[d] = ca[(size_t)t * INNER_ + tid * 4 + d];
      xmv[d] = xi[(size_t)t * 1536 + tid * 4 + d];
    }
    #pragma unroll
    for (int o = 0; o < 4; ++o) {
      const int cidx = tid * 4 + o;
      float q = bq[cidx], k = bk[cidx], v = bv[cidx];
      #pragma unroll
      for (int d = 0; d < 4; ++d) {
        q += cav[d] * Wq[tid * 16 + o * 4 + d];
        k += cav[d] * Wk[tid * 16 + o * 4 + d];
        v += xmv[d] * Wv[tid * 16 + o * 4 + d];
      }
      qs[cidx] = q; ks[cidx] = k; vs[cidx] = v;
      const int hm = cidx / DH_, dd = cidx % DH_;
      const size_t o2 = ((size_t)(b * NHM_ + hm) * S_ + s) * DH_ + dd;
      qbf[o2] = __float2bfloat16(q);
      kbf[o2] = __float2bfloat16(k);
      vbf[o2] = __float2bfloat16(v);
    }
  }
  __syncthreads();
  const int g = tid >> 5, l32 = tid & 31;
  const float* Wg = (g < 4) ? Wig : Wfg;
  const int h = g & 3;
  float sum = 0.f;
  for (int c = l32; c < INNER_; c += 32) {
    sum += qs[c] * Wg[h * 2304 + c]
         + ks[c] * Wg[h * 2304 + 768 + c]
         + vs[c] * Wg[h * 2304 + 1536 + c];
  }
  #pragma unroll
  for (int m = 16; m >= 1; m >>= 1) sum += __shfl_xor(sum, m);
  if (l32 == 0) {
    if (g < 4) ig[(size_t)(b * NHM_ + h) * S_ + s] = sum + big[h];
    else       fg[(size_t)(b * NHM_ + h) * S_ + s] = sum + bfg[h];
  }
}

// ---------------- per-(b,h) scans ------------------------------------------
__global__ __launch_bounds__(64) void gate_scan_k(
    const float* __restrict__ ig, const float* __restrict__ fg,
    float* __restrict__ lfc, float* __restrict__ aa, float* __restrict__ rm)
{
  const int bh = blockIdx.x;
  const int lane = threadIdx.x;
  const float* fgp = fg + bh * S_;
  const float* igp = ig + bh * S_;
  float v[16];
  float run = 0.f;
  #pragma unroll
  for (int i = 0; i < 16; ++i) {
    const float x = fgp[lane * 16 + i];
    const float lf = fminf(x, 0.f) - log1pf(expf(-fabsf(x)));
    run += lf;
    v[i] = run;
  }
  float inc = run;
  #pragma unroll
  for (int off = 1; off < 64; off <<= 1) {
    const float o = __shfl_up(inc, off);
    if (lane >= off) inc += o;
  }
  const float excl = inc - run;
  float rv[16];
  float rmx = -INFINITY;
  #pragma unroll
  for (int i = 0; i < 16; ++i) {
    const float l = v[i] + excl;
    lfc[bh * S_ + lane * 16 + i] = l;
    const float a = igp[lane * 16 + i] - l;
    aa[bh * S_ + lane * 16 + i] = a;
    rmx = fmaxf(rmx, a);
    rv[i] = rmx;
  }
  float incm = rmx;
  #pragma unroll
  for (int off = 1; off < 64; off <<= 1) {
    const float o = __shfl_up(incm, off);
    if (lane >= off) incm = fmaxf(incm, o);
  }
  float exm = __shfl_up(incm, 1);
  if (lane == 0) exm = -INFINITY;
  #pragma unroll
  for (int i = 0; i < 16; ++i) {
    rm[bh * S_ + lane * 16 + i] = fmaxf(rv[i], exm);
  }
}

// ---------------- mLSTM attention: partial kernel --------------------------
// grid (SLOTS_=40, 16 bh), 256 thr = 4 waves; wave w owns q-rows 64t+16w..+15.
// slot -> (t, chunk c); chunk covers 32-j tiles [c*8, min(c*8+8, 2t+2)).
// Writes additive partials: pacc[bh][slot][64][192] f32, rsp[bh][slot][64].
__global__ __launch_bounds__(256) void mlstm_part_k(
    const __hip_bfloat16* __restrict__ qbf, const __hip_bfloat16* __restrict__ kbf,
    const __hip_bfloat16* __restrict__ vbf,
    const float* __restrict__ aa, const float* __restrict__ rm,
    float* __restrict__ pacc, float* __restrict__ rsp)
{
  __shared__ __hip_bfloat16 Pl[4][16][40];
  const int bh = blockIdx.y;
  const int slot = blockIdx.x;
  int t = 0, base = 0;
  #pragma unroll
  for (int s = 0; s < 16; ++s) {
    const int sz = (s >> 2) + 1;
    if (slot >= base + sz) { base += sz; t = s + 1; }
  }
  const int c = slot - base;
  const int jt_lo = c * 8;
  const int jt_hi = min(jt_lo + 8, 2 * t + 2);

  const int wave = threadIdx.x >> 6, lane = threadIdx.x & 63;
  const int lrow = lane & 15, lgrp = lane >> 4;
  const int q0 = t * 64 + wave * 16;
  const __hip_bfloat16* Q  = qbf + (size_t)bh * S_ * DH_;
  const __hip_bfloat16* Kp = kbf + (size_t)bh * S_ * DH_;
  const __hip_bfloat16* Vp = vbf + (size_t)bh * S_ * DH_;
  const float* aap = aa + bh * S_;
  const float* rmp = rm + bh * S_;

  bf16x8v qf[6];
  #pragma unroll
  for (int kk = 0; kk < 6; ++kk)
    qf[kk] = *(const bf16x8v*)&Q[(size_t)(q0 + lrow) * DH_ + kk * 32 + lgrp * 8];
  float rmi[4];
  #pragma unroll
  for (int r = 0; r < 4; ++r) rmi[r] = rmp[q0 + lgrp * 4 + r];

  const f32x4 zero4 = {0.f, 0.f, 0.f, 0.f};
  f32x4 hacc[12];
  #pragma unroll
  for (int dd = 0; dd < 12; ++dd) hacc[dd] = zero4;
  float rs[4] = {0.f, 0.f, 0.f, 0.f};
  const float scale = 0.07216878364870323f;   // 1/sqrt(192)

  for (int jt = jt_lo; jt < jt_hi; ++jt) {
    const int j0 = jt * 32;
    // QK^T
    f32x4 sacc[2];
    sacc[0] = zero4; sacc[1] = zero4;
    #pragma unroll
    for (int jj = 0; jj < 2; ++jj) {
      #pragma unroll
      for (int kk = 0; kk < 6; ++kk) {
        const bf16x8v kf = *(const bf16x8v*)
            &Kp[(size_t)(j0 + jj * 16 + lrow) * DH_ + kk * 32 + lgrp * 8];
        sacc[jj] = mfma16(qf[kk], kf, sacc[jj]);
      }
    }
    // weights + rowsum + P tile (per-wave private LDS)
    #pragma unroll
    for (int jj = 0; jj < 2; ++jj) {
      const int j = j0 + jj * 16 + lrow;
      const float aj = aap[j];
      #pragma unroll
      for (int r = 0; r < 4; ++r) {
        const int i_ = q0 + lgrp * 4 + r;
        float cval = 0.f;
        if (j <= i_) cval = sacc[jj][r] * scale * __expf(aj - rmi[r]);
        rs[r] += cval;
        Pl[wave][lgrp * 4 + r][jj * 16 + lrow] = __float2bfloat16(cval);
      }
    }
    __syncthreads();
    const bf16x8v pf = *(const bf16x8v*)&Pl[wave][lrow][lgrp * 8];
    // PV: V B-fragments gathered straight from global (L2-resident)
    #pragma unroll
    for (int dd = 0; dd < 12; ++dd) {
      const __hip_bfloat16* vb = &Vp[(size_t)(j0 + lgrp * 8) * DH_ + dd * 16 + lrow];
      bf16x8v vf;
      #pragma unroll
      for (int e = 0; e < 8; ++e) vf[e] = *(const __bf16*)&vb[(size_t)e * DH_];
      hacc[dd] = mfma16(pf, vf, hacc[dd]);
    }
    __syncthreads();
  }

  // rowsum reduce across 16 lrow lanes
  #pragma unroll
  for (int r = 0; r < 4; ++r) {
    #pragma unroll
    for (int m = 1; m < 16; m <<= 1) rs[r] += __shfl_xor(rs[r], m);
  }
  // write partials
  const size_t pbase = ((size_t)bh * SLOTS_ + slot) * 64;
  #pragma unroll
  for (int dd = 0; dd < 12; ++dd) {
    #pragma unroll
    for (int r = 0; r < 4; ++r) {
      pacc[(pbase + wave * 16 + lgrp * 4 + r) * 192 + dd * 16 + lrow] = hacc[dd][r];
    }
  }
  if (lrow == 0) {
    #pragma unroll
    for (int r = 0; r < 4; ++r)
      rsp[pbase + wave * 16 + lgrp * 4 + r] = rs[r];
  }
}

// ---------------- mLSTM reduce + fused epilogue ----------------------------
// grid (16 t, 16 bh), 256 thr = 4 waves; same lane layout as partial kernel.
__global__ __launch_bounds__(256) void mlstm_red_k(
    const float* __restrict__ pacc, const float* __restrict__ rsp,
    const float* __restrict__ lfc, const float* __restrict__ rm,
    const float* __restrict__ ca, const float* __restrict__ xi,
    const float* __restrict__ nw, const float* __restrict__ nb,
    const float* __restrict__ skip, float* __restrict__ hs)
{
  const int t = blockIdx.x, bh = blockIdx.y;
  const int b = bh >> 2, hm = bh & 3;
  int base = 0;
  #pragma unroll
  for (int s = 0; s < 16; ++s) if (s < t) base += (s >> 2) + 1;
  const int nc = (t >> 2) + 1;

  const int wave = threadIdx.x >> 6, lane = threadIdx.x & 63;
  const int lrow = lane & 15, lgrp = lane >> 4;
  const int q0 = t * 64 + wave * 16;
  const float* lfcp = lfc + bh * S_;
  const float* rmp  = rm + bh * S_;

  float hsum[12][4];
  #pragma unroll
  for (int dd = 0; dd < 12; ++dd)
    #pragma unroll
    for (int r = 0; r < 4; ++r) hsum[dd][r] = 0.f;
  float rst[4] = {0.f, 0.f, 0.f, 0.f};

  for (int cc = 0; cc < nc; ++cc) {
    const size_t pbase = ((size_t)bh * SLOTS_ + base + cc) * 64;
    #pragma unroll
    for (int dd = 0; dd < 12; ++dd) {
      #pragma unroll
      for (int r = 0; r < 4; ++r) {
        hsum[dd][r] += pacc[(pbase + wave * 16 + lgrp * 4 + r) * 192 + dd * 16 + lrow];
      }
    }
    #pragma unroll
    for (int r = 0; r < 4; ++r)
      rst[r] += rsp[pbase + wave * 16 + lgrp * 4 + r];
  }

  #pragma unroll
  for (int r = 0; r < 4; ++r) {
    const int i_ = q0 + lgrp * 4 + r;
    const int tok = b * S_ + i_;
    const float mld = lfcp[i_] + rmp[i_];
    const float nrm = fmaxf(fabsf(rst[r]), __expf(-mld)) + 1e-6f;
    float hv[12];
    float sum = 0.f, sq = 0.f;
    #pragma unroll
    for (int dd = 0; dd < 12; ++dd) {
      const float x = hsum[dd][r] / nrm;
      hv[dd] = x; sum += x; sq += x * x;
    }
    #pragma unroll
    for (int m = 1; m < 16; m <<= 1) {
      sum += __shfl_xor(sum, m);
      sq  += __shfl_xor(sq, m);
    }
    const float mean = sum * (1.f / 192.f);
    const float var  = sq * (1.f / 192.f) - mean * mean;
    const float rstd = rsqrtf(var + 1e-5f);
    #pragma unroll
    for (int dd = 0; dd < 12; ++dd) {
      const int cidx = hm * DH_ + dd * 16 + lrow;
      const float hn = (hv[dd] - mean) * rstd * nw[cidx] + nb[cidx];
      const float cav = ca[(size_t)tok * INNER_ + cidx];
      const float zz  = xi[(size_t)tok * 1536 + 768 + cidx];
      const float hsv = (hn + skip[cidx] * cav) * (zz / (1.f + __expf(-zz)));
      hs[(size_t)tok * INNER_ + cidx] = hsv;
    }
  }
}

// ---------------------------------------------------------------------------
extern "C" void kernel_launch(void* const* d_in, const int* in_sizes, int n_in,
                              void* d_out, int out_size, void* d_ws, size_t ws_size,
                              hipStream_t stream) {
  const float* x      = (const float*)d_in[0];
  const float* W_up   = (const float*)d_in[1];
  const float* b_up   = (const float*)d_in[2];
  const float* Wq     = (const float*)d_in[3];
  const float* bq     = (const float*)d_in[4];
  const float* Wk     = (const float*)d_in[5];
  const float* bk     = (const float*)d_in[6];
  const float* Wv     = (const float*)d_in[7];
  const float* bv     = (const float*)d_in[8];
  const float* conv_w = (const float*)d_in[9];
  const float* conv_b = (const float*)d_in[10];
  const float* W_ig   = (const float*)d_in[11];
  const float* b_ig   = (const float*)d_in[12];
  const float* W_fg   = (const float*)d_in[13];
  const float* b_fg   = (const float*)d_in[14];
  const float* norm_w = (const float*)d_in[15];
  const float* norm_b = (const float*)d_in[16];
  const float* skip   = (const float*)d_in[17];
  const float* W_down = (const float*)d_in[18];
  const float* b_down = (const float*)d_in[19];
  float* out = (float*)d_out;

  char* ws = (char*)d_ws;
  constexpr size_t OFF_XI  = 0;
  constexpr size_t OFF_CA  = OFF_XI + (size_t)NTOK * 1536 * 4;
  constexpr size_t OFF_QBF = OFF_CA + (size_t)NTOK * INNER_ * 4;
  constexpr size_t OFF_KBF = OFF_QBF + (size_t)16 * S_ * DH_ * 2;
  constexpr size_t OFF_VBF = OFF_KBF + (size_t)16 * S_ * DH_ * 2;
  constexpr size_t OFF_IG  = OFF_VBF + (size_t)16 * S_ * DH_ * 2;
  constexpr size_t OFF_FG  = OFF_IG + (size_t)16 * S_ * 4;
  constexpr size_t OFF_LFC = OFF_FG + (size_t)16 * S_ * 4;
  constexpr size_t OFF_AA  = OFF_LFC + (size_t)16 * S_ * 4;
  constexpr size_t OFF_RM  = OFF_AA + (size_t)16 * S_ * 4;
  constexpr size_t OFF_HS  = OFF_RM + (size_t)16 * S_ * 4;
  constexpr size_t OFF_XB  = OFF_HS + (size_t)NTOK * INNER_ * 4;   // bf16 x
  constexpr size_t OFF_WUB = OFF_XB + (size_t)NTOK * DIM_ * 2;     // bf16 W_up
  constexpr size_t OFF_PAC = OFF_WUB + (size_t)1536 * DIM_ * 2;    // partials
  constexpr size_t OFF_RSP = OFF_PAC + (size_t)16 * SLOTS_ * 64 * 192 * 4;

  float* x_inner = (float*)(ws + OFF_XI);
  float* conv_a  = (float*)(ws + OFF_CA);
  __hip_bfloat16* qbf = (__hip_bfloat16*)(ws + OFF_QBF);
  __hip_bfloat16* kbf = (__hip_bfloat16*)(ws + OFF_KBF);
  __hip_bfloat16* vbf = (__hip_bfloat16*)(ws + OFF_VBF);
  float* ig  = (float*)(ws + OFF_IG);
  float* fg  = (float*)(ws + OFF_FG);
  float* lfc = (float*)(ws + OFF_LFC);
  float* aav = (float*)(ws + OFF_AA);
  float* rmv = (float*)(ws + OFF_RM);
  float* hs  = (float*)(ws + OFF_HS);
  __hip_bfloat16* xb  = (__hip_bfloat16*)(ws + OFF_XB);
  __hip_bfloat16* wub = (__hip_bfloat16*)(ws + OFF_WUB);
  float* pacc = (float*)(ws + OFF_PAC);
  float* rsp  = (float*)(ws + OFF_RSP);

  // 0) cast x, W_up to bf16
  cast_bf16_k<<<(NTOK * DIM_ / 4 + 255) / 256, 256, 0, stream>>>(x, xb, NTOK * DIM_ / 4);
  cast_bf16_k<<<(1536 * DIM_ / 4 + 255) / 256, 256, 0, stream>>>(W_up, wub, 1536 * DIM_ / 4);
  // 1) up-projection (bf16 MFMA, fp32 accum)
  gemm_up_k<<<dim3(12, 64), 256, 0, stream>>>(xb, wub, b_up, x_inner);
  // 2) depthwise conv + SiLU
  conv_silu_k<<<(NTOK * INNER_) / 256, 256, 0, stream>>>(x_inner, conv_w, conv_b, conv_a);
  // 3) headwise q,k,v + gates
  headwise_gates_k<<<NTOK, 256, 0, stream>>>(
      x_inner, conv_a, Wq, bq, Wk, bk, Wv, bv, W_ig, b_ig, W_fg, b_fg,
      qbf, kbf, vbf, ig, fg);
  // 4) gate scans
  gate_scan_k<<<16, 64, 0, stream>>>(ig, fg, lfc, aav, rmv);
  // 5a) attention partials (balanced split-j)
  mlstm_part_k<<<dim3(SLOTS_, 16), 256, 0, stream>>>(qbf, kbf, vbf, aav, rmv, pacc, rsp);
  // 5b) reduce + normalizer + groupnorm + skip + z-gate
  mlstm_red_k<<<dim3(16, 16), 256, 0, stream>>>(
      pacc, rsp, lfc, rmv, conv_a, x_inner, norm_w, norm_b, skip, hs);
  // 6) down-projection fp32
  gemm_rt<float><<<dim3(DIM_ / 64, NTOK / 64), 256, 0, stream>>>(
      hs, W_down, b_down, out, NTOK, DIM_, INNER_);
}

// Round 4
// 239.739 us; speedup vs baseline: 1.7089x; 1.1570x over previous
//
#include <hip/hip_runtime.h>
#include <hip/hip_bf16.h>

// ---------------------------------------------------------------------------
// ViLLayer forward, round 3: down-proj -> bf16 MFMA (fp32 accum).
//   epilogue writes h_state directly as bf16; W_down pre-cast to bf16.
// ---------------------------------------------------------------------------

#define B_     4
#define S_     1024
#define DIM_   384
#define INNER_ 768
#define NHM_   4
#define DH_    192
#define NTOK   (B_*S_)      // 4096
#define SLOTS_ 40           // sum over t of ceil((t+1)/4)

typedef __attribute__((ext_vector_type(8))) __bf16 bf16x8v;
typedef __attribute__((ext_vector_type(4))) float  f32x4;

static __device__ __forceinline__ f32x4 mfma16(bf16x8v a, bf16x8v b, f32x4 c) {
  return __builtin_amdgcn_mfma_f32_16x16x32_bf16(a, b, c, 0, 0, 0);
}

// ---------------- cast fp32 -> bf16 (vectorized) ---------------------------
__global__ __launch_bounds__(256) void cast_bf16_k(
    const float* __restrict__ in, __hip_bfloat16* __restrict__ out, int n4)
{
  const int i = blockIdx.x * 256 + threadIdx.x;
  if (i >= n4) return;
  const float4 v = *(const float4*)&in[i * 4];
  out[i * 4 + 0] = __float2bfloat16(v.x);
  out[i * 4 + 1] = __float2bfloat16(v.y);
  out[i * 4 + 2] = __float2bfloat16(v.z);
  out[i * 4 + 3] = __float2bfloat16(v.w);
}

// ---------------- up-proj: bf16 MFMA GEMM ----------------------------------
// C[4096][1536] = xb[4096][384] @ Wb[1536][384]^T + b.  BM=64, BN=128.
__global__ __launch_bounds__(256) void gemm_up_k(
    const __hip_bfloat16* __restrict__ xb, const __hip_bfloat16* __restrict__ Wb,
    const float* __restrict__ bias, float* __restrict__ C)
{
  const int n0 = blockIdx.x * 128, m0 = blockIdx.y * 64;
  const int wave = threadIdx.x >> 6, lane = threadIdx.x & 63;
  const int lrow = lane & 15, lgrp = lane >> 4;
  const __hip_bfloat16* xr = xb + (size_t)(m0 + wave * 16 + lrow) * DIM_;
  f32x4 acc[8];
  #pragma unroll
  for (int nt = 0; nt < 8; ++nt) acc[nt] = f32x4{0.f, 0.f, 0.f, 0.f};
  for (int k0 = 0; k0 < DIM_; k0 += 32) {
    const bf16x8v af = *(const bf16x8v*)&xr[k0 + lgrp * 8];
    #pragma unroll
    for (int nt = 0; nt < 8; ++nt) {
      const bf16x8v bf = *(const bf16x8v*)
          &Wb[(size_t)(n0 + nt * 16 + lrow) * DIM_ + k0 + lgrp * 8];
      acc[nt] = mfma16(af, bf, acc[nt]);
    }
  }
  #pragma unroll
  for (int nt = 0; nt < 8; ++nt) {
    const int n = n0 + nt * 16 + lrow;
    const float bv = bias[n];
    #pragma unroll
    for (int r = 0; r < 4; ++r) {
      const int m = m0 + wave * 16 + lgrp * 4 + r;
      C[(size_t)m * 1536 + n] = acc[nt][r] + bv;
    }
  }
}

// ---------------- down-proj: bf16 MFMA GEMM --------------------------------
// out[4096][384] = hsb[4096][768] @ Wdb[384][768]^T + b.  BM=64, BN=128.
// grid (384/128, 4096/64) = (3,64), 256 thr = 4 waves.
__global__ __launch_bounds__(256) void gemm_down_k(
    const __hip_bfloat16* __restrict__ hsb, const __hip_bfloat16* __restrict__ Wdb,
    const float* __restrict__ bias, float* __restrict__ C)
{
  const int n0 = blockIdx.x * 128, m0 = blockIdx.y * 64;
  const int wave = threadIdx.x >> 6, lane = threadIdx.x & 63;
  const int lrow = lane & 15, lgrp = lane >> 4;
  const __hip_bfloat16* ar = hsb + (size_t)(m0 + wave * 16 + lrow) * INNER_;
  f32x4 acc[8];
  #pragma unroll
  for (int nt = 0; nt < 8; ++nt) acc[nt] = f32x4{0.f, 0.f, 0.f, 0.f};
  for (int k0 = 0; k0 < INNER_; k0 += 32) {
    const bf16x8v af = *(const bf16x8v*)&ar[k0 + lgrp * 8];
    #pragma unroll
    for (int nt = 0; nt < 8; ++nt) {
      const bf16x8v bf = *(const bf16x8v*)
          &Wdb[(size_t)(n0 + nt * 16 + lrow) * INNER_ + k0 + lgrp * 8];
      acc[nt] = mfma16(af, bf, acc[nt]);
    }
  }
  #pragma unroll
  for (int nt = 0; nt < 8; ++nt) {
    const int n = n0 + nt * 16 + lrow;
    const float bv = bias[n];
    #pragma unroll
    for (int r = 0; r < 4; ++r) {
      const int m = m0 + wave * 16 + lgrp * 4 + r;
      C[(size_t)m * DIM_ + n] = acc[nt][r] + bv;
    }
  }
}

// ---------------- depthwise 3x3 conv + bias + SiLU -------------------------
__global__ __launch_bounds__(256) void conv_silu_k(
    const float* __restrict__ xi, const float* __restrict__ cw,
    const float* __restrict__ cb, float* __restrict__ ca)
{
  const int idx = blockIdx.x * 256 + threadIdx.x;
  if (idx >= NTOK * INNER_) return;
  const int c = idx % INNER_;
  const int t = idx / INNER_;
  const int s = t & 1023;
  const int y = s >> 5, x = s & 31;
  const int tb = t - s;
  float acc = cb[c];
  #pragma unroll
  for (int ky = -1; ky <= 1; ++ky) {
    const int yy = y + ky;
    if (yy < 0 || yy > 31) continue;
    #pragma unroll
    for (int kx = -1; kx <= 1; ++kx) {
      const int xx = x + kx;
      if (xx < 0 || xx > 31) continue;
      acc += xi[(size_t)(tb + (yy << 5) + xx) * 1536 + c]
           * cw[((ky + 1) * 3 + (kx + 1)) * INNER_ + c];
    }
  }
  ca[(size_t)t * INNER_ + c] = acc / (1.f + __expf(-acc));
}

// ---------------- headwise q,k,v + gate pre-activations --------------------
__global__ __launch_bounds__(256) void headwise_gates_k(
    const float* __restrict__ xi, const float* __restrict__ ca,
    const float* __restrict__ Wq, const float* __restrict__ bq,
    const float* __restrict__ Wk, const float* __restrict__ bk,
    const float* __restrict__ Wv, const float* __restrict__ bv,
    const float* __restrict__ Wig, const float* __restrict__ big,
    const float* __restrict__ Wfg, const float* __restrict__ bfg,
    __hip_bfloat16* __restrict__ qbf, __hip_bfloat16* __restrict__ kbf,
    __hip_bfloat16* __restrict__ vbf,
    float* __restrict__ ig, float* __restrict__ fg)
{
  __shared__ float qs[INNER_], ks[INNER_], vs[INNER_];
  const int t = blockIdx.x;
  const int b = t >> 10, s = t & 1023;
  const int tid = threadIdx.x;
  if (tid < 192) {
    float cav[4], xmv[4];
    #pragma unroll
    for (int d = 0; d < 4; ++d) {
      cav[d] = ca[(size_t)t * INNER_ + tid * 4 + d];
      xmv[d] = xi[(size_t)t * 1536 + tid * 4 + d];
    }
    #pragma unroll
    for (int o = 0; o < 4; ++o) {
      const int cidx = tid * 4 + o;
      float q = bq[cidx], k = bk[cidx], v = bv[cidx];
      #pragma unroll
      for (int d = 0; d < 4; ++d) {
        q += cav[d] * Wq[tid * 16 + o * 4 + d];
        k += cav[d] * Wk[tid * 16 + o * 4 + d];
        v += xmv[d] * Wv[tid * 16 + o * 4 + d];
      }
      qs[cidx] = q; ks[cidx] = k; vs[cidx] = v;
      const int hm = cidx / DH_, dd = cidx % DH_;
      const size_t o2 = ((size_t)(b * NHM_ + hm) * S_ + s) * DH_ + dd;
      qbf[o2] = __float2bfloat16(q);
      kbf[o2] = __float2bfloat16(k);
      vbf[o2] = __float2bfloat16(v);
    }
  }
  __syncthreads();
  const int g = tid >> 5, l32 = tid & 31;
  const float* Wg = (g < 4) ? Wig : Wfg;
  const int h = g & 3;
  float sum = 0.f;
  for (int c = l32; c < INNER_; c += 32) {
    sum += qs[c] * Wg[h * 2304 + c]
         + ks[c] * Wg[h * 2304 + 768 + c]
         + vs[c] * Wg[h * 2304 + 1536 + c];
  }
  #pragma unroll
  for (int m = 16; m >= 1; m >>= 1) sum += __shfl_xor(sum, m);
  if (l32 == 0) {
    if (g < 4) ig[(size_t)(b * NHM_ + h) * S_ + s] = sum + big[h];
    else       fg[(size_t)(b * NHM_ + h) * S_ + s] = sum + bfg[h];
  }
}

// ---------------- per-(b,h) scans ------------------------------------------
__global__ __launch_bounds__(64) void gate_scan_k(
    const float* __restrict__ ig, const float* __restrict__ fg,
    float* __restrict__ lfc, float* __restrict__ aa, float* __restrict__ rm)
{
  const int bh = blockIdx.x;
  const int lane = threadIdx.x;
  const float* fgp = fg + bh * S_;
  const float* igp = ig + bh * S_;
  float v[16];
  float run = 0.f;
  #pragma unroll
  for (int i = 0; i < 16; ++i) {
    const float x = fgp[lane * 16 + i];
    const float lf = fminf(x, 0.f) - log1pf(expf(-fabsf(x)));
    run += lf;
    v[i] = run;
  }
  float inc = run;
  #pragma unroll
  for (int off = 1; off < 64; off <<= 1) {
    const float o = __shfl_up(inc, off);
    if (lane >= off) inc += o;
  }
  const float excl = inc - run;
  float rv[16];
  float rmx = -INFINITY;
  #pragma unroll
  for (int i = 0; i < 16; ++i) {
    const float l = v[i] + excl;
    lfc[bh * S_ + lane * 16 + i] = l;
    const float a = igp[lane * 16 + i] - l;
    aa[bh * S_ + lane * 16 + i] = a;
    rmx = fmaxf(rmx, a);
    rv[i] = rmx;
  }
  float incm = rmx;
  #pragma unroll
  for (int off = 1; off < 64; off <<= 1) {
    const float o = __shfl_up(incm, off);
    if (lane >= off) incm = fmaxf(incm, o);
  }
  float exm = __shfl_up(incm, 1);
  if (lane == 0) exm = -INFINITY;
  #pragma unroll
  for (int i = 0; i < 16; ++i) {
    rm[bh * S_ + lane * 16 + i] = fmaxf(rv[i], exm);
  }
}

// ---------------- mLSTM attention: partial kernel --------------------------
__global__ __launch_bounds__(256) void mlstm_part_k(
    const __hip_bfloat16* __restrict__ qbf, const __hip_bfloat16* __restrict__ kbf,
    const __hip_bfloat16* __restrict__ vbf,
    const float* __restrict__ aa, const float* __restrict__ rm,
    float* __restrict__ pacc, float* __restrict__ rsp)
{
  __shared__ __hip_bfloat16 Pl[4][16][40];
  const int bh = blockIdx.y;
  const int slot = blockIdx.x;
  int t = 0, base = 0;
  #pragma unroll
  for (int s = 0; s < 16; ++s) {
    const int sz = (s >> 2) + 1;
    if (slot >= base + sz) { base += sz; t = s + 1; }
  }
  const int c = slot - base;
  const int jt_lo = c * 8;
  const int jt_hi = min(jt_lo + 8, 2 * t + 2);

  const int wave = threadIdx.x >> 6, lane = threadIdx.x & 63;
  const int lrow = lane & 15, lgrp = lane >> 4;
  const int q0 = t * 64 + wave * 16;
  const __hip_bfloat16* Q  = qbf + (size_t)bh * S_ * DH_;
  const __hip_bfloat16* Kp = kbf + (size_t)bh * S_ * DH_;
  const __hip_bfloat16* Vp = vbf + (size_t)bh * S_ * DH_;
  const float* aap = aa + bh * S_;
  const float* rmp = rm + bh * S_;

  bf16x8v qf[6];
  #pragma unroll
  for (int kk = 0; kk < 6; ++kk)
    qf[kk] = *(const bf16x8v*)&Q[(size_t)(q0 + lrow) * DH_ + kk * 32 + lgrp * 8];
  float rmi[4];
  #pragma unroll
  for (int r = 0; r < 4; ++r) rmi[r] = rmp[q0 + lgrp * 4 + r];

  const f32x4 zero4 = {0.f, 0.f, 0.f, 0.f};
  f32x4 hacc[12];
  #pragma unroll
  for (int dd = 0; dd < 12; ++dd) hacc[dd] = zero4;
  float rs[4] = {0.f, 0.f, 0.f, 0.f};
  const float scale = 0.07216878364870323f;   // 1/sqrt(192)

  for (int jt = jt_lo; jt < jt_hi; ++jt) {
    const int j0 = jt * 32;
    f32x4 sacc[2];
    sacc[0] = zero4; sacc[1] = zero4;
    #pragma unroll
    for (int jj = 0; jj < 2; ++jj) {
      #pragma unroll
      for (int kk = 0; kk < 6; ++kk) {
        const bf16x8v kf = *(const bf16x8v*)
            &Kp[(size_t)(j0 + jj * 16 + lrow) * DH_ + kk * 32 + lgrp * 8];
        sacc[jj] = mfma16(qf[kk], kf, sacc[jj]);
      }
    }
    #pragma unroll
    for (int jj = 0; jj < 2; ++jj) {
      const int j = j0 + jj * 16 + lrow;
      const float aj = aap[j];
      #pragma unroll
      for (int r = 0; r < 4; ++r) {
        const int i_ = q0 + lgrp * 4 + r;
        float cval = 0.f;
        if (j <= i_) cval = sacc[jj][r] * scale * __expf(aj - rmi[r]);
        rs[r] += cval;
        Pl[wave][lgrp * 4 + r][jj * 16 + lrow] = __float2bfloat16(cval);
      }
    }
    __syncthreads();
    const bf16x8v pf = *(const bf16x8v*)&Pl[wave][lrow][lgrp * 8];
    #pragma unroll
    for (int dd = 0; dd < 12; ++dd) {
      const __hip_bfloat16* vb = &Vp[(size_t)(j0 + lgrp * 8) * DH_ + dd * 16 + lrow];
      bf16x8v vf;
      #pragma unroll
      for (int e = 0; e < 8; ++e) vf[e] = *(const __bf16*)&vb[(size_t)e * DH_];
      hacc[dd] = mfma16(pf, vf, hacc[dd]);
    }
    __syncthreads();
  }

  #pragma unroll
  for (int r = 0; r < 4; ++r) {
    #pragma unroll
    for (int m = 1; m < 16; m <<= 1) rs[r] += __shfl_xor(rs[r], m);
  }
  const size_t pbase = ((size_t)bh * SLOTS_ + slot) * 64;
  #pragma unroll
  for (int dd = 0; dd < 12; ++dd) {
    #pragma unroll
    for (int r = 0; r < 4; ++r) {
      pacc[(pbase + wave * 16 + lgrp * 4 + r) * 192 + dd * 16 + lrow] = hacc[dd][r];
    }
  }
  if (lrow == 0) {
    #pragma unroll
    for (int r = 0; r < 4; ++r)
      rsp[pbase + wave * 16 + lgrp * 4 + r] = rs[r];
  }
}

// ---------------- mLSTM reduce + fused epilogue (bf16 h_state out) ---------
__global__ __launch_bounds__(256) void mlstm_red_k(
    const float* __restrict__ pacc, const float* __restrict__ rsp,
    const float* __restrict__ lfc, const float* __restrict__ rm,
    const float* __restrict__ ca, const float* __restrict__ xi,
    const float* __restrict__ nw, const float* __restrict__ nb,
    const float* __restrict__ skip, __hip_bfloat16* __restrict__ hs)
{
  const int t = blockIdx.x, bh = blockIdx.y;
  const int b = bh >> 2, hm = bh & 3;
  int base = 0;
  #pragma unroll
  for (int s = 0; s < 16; ++s) if (s < t) base += (s >> 2) + 1;
  const int nc = (t >> 2) + 1;

  const int wave = threadIdx.x >> 6, lane = threadIdx.x & 63;
  const int lrow = lane & 15, lgrp = lane >> 4;
  const int q0 = t * 64 + wave * 16;
  const float* lfcp = lfc + bh * S_;
  const float* rmp  = rm + bh * S_;

  float hsum[12][4];
  #pragma unroll
  for (int dd = 0; dd < 12; ++dd)
    #pragma unroll
    for (int r = 0; r < 4; ++r) hsum[dd][r] = 0.f;
  float rst[4] = {0.f, 0.f, 0.f, 0.f};

  for (int cc = 0; cc < nc; ++cc) {
    const size_t pbase = ((size_t)bh * SLOTS_ + base + cc) * 64;
    #pragma unroll
    for (int dd = 0; dd < 12; ++dd) {
      #pragma unroll
      for (int r = 0; r < 4; ++r) {
        hsum[dd][r] += pacc[(pbase + wave * 16 + lgrp * 4 + r) * 192 + dd * 16 + lrow];
      }
    }
    #pragma unroll
    for (int r = 0; r < 4; ++r)
      rst[r] += rsp[pbase + wave * 16 + lgrp * 4 + r];
  }

  #pragma unroll
  for (int r = 0; r < 4; ++r) {
    const int i_ = q0 + lgrp * 4 + r;
    const int tok = b * S_ + i_;
    const float mld = lfcp[i_] + rmp[i_];
    const float nrm = fmaxf(fabsf(rst[r]), __expf(-mld)) + 1e-6f;
    float hv[12];
    float sum = 0.f, sq = 0.f;
    #pragma unroll
    for (int dd = 0; dd < 12; ++dd) {
      const float x = hsum[dd][r] / nrm;
      hv[dd] = x; sum += x; sq += x * x;
    }
    #pragma unroll
    for (int m = 1; m < 16; m <<= 1) {
      sum += __shfl_xor(sum, m);
      sq  += __shfl_xor(sq, m);
    }
    const float mean = sum * (1.f / 192.f);
    const float var  = sq * (1.f / 192.f) - mean * mean;
    const float rstd = rsqrtf(var + 1e-5f);
    #pragma unroll
    for (int dd = 0; dd < 12; ++dd) {
      const int cidx = hm * DH_ + dd * 16 + lrow;
      const float hn = (hv[dd] - mean) * rstd * nw[cidx] + nb[cidx];
      const float cav = ca[(size_t)tok * INNER_ + cidx];
      const float zz  = xi[(size_t)tok * 1536 + 768 + cidx];
      const float hsv = (hn + skip[cidx] * cav) * (zz / (1.f + __expf(-zz)));
      hs[(size_t)tok * INNER_ + cidx] = __float2bfloat16(hsv);
    }
  }
}

// ---------------------------------------------------------------------------
extern "C" void kernel_launch(void* const* d_in, const int* in_sizes, int n_in,
                              void* d_out, int out_size, void* d_ws, size_t ws_size,
                              hipStream_t stream) {
  const float* x      = (const float*)d_in[0];
  const float* W_up   = (const float*)d_in[1];
  const float* b_up   = (const float*)d_in[2];
  const float* Wq     = (const float*)d_in[3];
  const float* bq     = (const float*)d_in[4];
  const float* Wk     = (const float*)d_in[5];
  const float* bk     = (const float*)d_in[6];
  const float* Wv     = (const float*)d_in[7];
  const float* bv     = (const float*)d_in[8];
  const float* conv_w = (const float*)d_in[9];
  const float* conv_b = (const float*)d_in[10];
  const float* W_ig   = (const float*)d_in[11];
  const float* b_ig   = (const float*)d_in[12];
  const float* W_fg   = (const float*)d_in[13];
  const float* b_fg   = (const float*)d_in[14];
  const float* norm_w = (const float*)d_in[15];
  const float* norm_b = (const float*)d_in[16];
  const float* skip   = (const float*)d_in[17];
  const float* W_down = (const float*)d_in[18];
  const float* b_down = (const float*)d_in[19];
  float* out = (float*)d_out;

  char* ws = (char*)d_ws;
  constexpr size_t OFF_XI  = 0;
  constexpr size_t OFF_CA  = OFF_XI + (size_t)NTOK * 1536 * 4;
  constexpr size_t OFF_QBF = OFF_CA + (size_t)NTOK * INNER_ * 4;
  constexpr size_t OFF_KBF = OFF_QBF + (size_t)16 * S_ * DH_ * 2;
  constexpr size_t OFF_VBF = OFF_KBF + (size_t)16 * S_ * DH_ * 2;
  constexpr size_t OFF_IG  = OFF_VBF + (size_t)16 * S_ * DH_ * 2;
  constexpr size_t OFF_FG  = OFF_IG + (size_t)16 * S_ * 4;
  constexpr size_t OFF_LFC = OFF_FG + (size_t)16 * S_ * 4;
  constexpr size_t OFF_AA  = OFF_LFC + (size_t)16 * S_ * 4;
  constexpr size_t OFF_RM  = OFF_AA + (size_t)16 * S_ * 4;
  constexpr size_t OFF_HS  = OFF_RM + (size_t)16 * S_ * 4;          // bf16 h_state
  constexpr size_t OFF_XB  = OFF_HS + (size_t)NTOK * INNER_ * 4;    // bf16 x
  constexpr size_t OFF_WUB = OFF_XB + (size_t)NTOK * DIM_ * 2;      // bf16 W_up
  constexpr size_t OFF_PAC = OFF_WUB + (size_t)1536 * DIM_ * 2;     // partials
  constexpr size_t OFF_RSP = OFF_PAC + (size_t)16 * SLOTS_ * 64 * 192 * 4;
  constexpr size_t OFF_WDB = OFF_RSP + (size_t)16 * SLOTS_ * 64 * 4; // bf16 W_down

  float* x_inner = (float*)(ws + OFF_XI);
  float* conv_a  = (float*)(ws + OFF_CA);
  __hip_bfloat16* qbf = (__hip_bfloat16*)(ws + OFF_QBF);
  __hip_bfloat16* kbf = (__hip_bfloat16*)(ws + OFF_KBF);
  __hip_bfloat16* vbf = (__hip_bfloat16*)(ws + OFF_VBF);
  float* ig  = (float*)(ws + OFF_IG);
  float* fg  = (float*)(ws + OFF_FG);
  float* lfc = (float*)(ws + OFF_LFC);
  float* aav = (float*)(ws + OFF_AA);
  float* rmv = (float*)(ws + OFF_RM);
  __hip_bfloat16* hsb = (__hip_bfloat16*)(ws + OFF_HS);
  __hip_bfloat16* xb  = (__hip_bfloat16*)(ws + OFF_XB);
  __hip_bfloat16* wub = (__hip_bfloat16*)(ws + OFF_WUB);
  float* pacc = (float*)(ws + OFF_PAC);
  float* rsp  = (float*)(ws + OFF_RSP);
  __hip_bfloat16* wdb = (__hip_bfloat16*)(ws + OFF_WDB);

  // 0) casts
  cast_bf16_k<<<(NTOK * DIM_ / 4 + 255) / 256, 256, 0, stream>>>(x, xb, NTOK * DIM_ / 4);
  cast_bf16_k<<<(1536 * DIM_ / 4 + 255) / 256, 256, 0, stream>>>(W_up, wub, 1536 * DIM_ / 4);
  cast_bf16_k<<<(DIM_ * INNER_ / 4 + 255) / 256, 256, 0, stream>>>(W_down, wdb, DIM_ * INNER_ / 4);
  // 1) up-projection (bf16 MFMA, fp32 accum)
  gemm_up_k<<<dim3(12, 64), 256, 0, stream>>>(xb, wub, b_up, x_inner);
  // 2) depthwise conv + SiLU
  conv_silu_k<<<(NTOK * INNER_) / 256, 256, 0, stream>>>(x_inner, conv_w, conv_b, conv_a);
  // 3) headwise q,k,v + gates
  headwise_gates_k<<<NTOK, 256, 0, stream>>>(
      x_inner, conv_a, Wq, bq, Wk, bk, Wv, bv, W_ig, b_ig, W_fg, b_fg,
      qbf, kbf, vbf, ig, fg);
  // 4) gate scans
  gate_scan_k<<<16, 64, 0, stream>>>(ig, fg, lfc, aav, rmv);
  // 5a) attention partials
  mlstm_part_k<<<dim3(SLOTS_, 16), 256, 0, stream>>>(qbf, kbf, vbf, aav, rmv, pacc, rsp);
  // 5b) reduce + epilogue (bf16 h_state)
  mlstm_red_k<<<dim3(16, 16), 256, 0, stream>>>(
      pacc, rsp, lfc, rmv, conv_a, x_inner, norm_w, norm_b, skip, hsb);
  // 6) down-projection (bf16 MFMA, fp32 out)
  gemm_down_k<<<dim3(3, 64), 256, 0, stream>>>(hsb, wdb, b_down, out);
}